// Round 13
// baseline (354.462 us; speedup 1.0000x reference)
//
#include <hip/hip_runtime.h>
#include <hip/hip_fp16.h>

// GCN 2-layer + FC. Round 13: (a) fp16 packed (pk_fma) accumulation in both
// gathers (4-5 VALU ops/16B vs 12, halved shfl tails); (b) gather128 fused
// with MFMA GEMM2 via LDS tile (kills Ah1 round-trip + one launch).
// Front-end L1/L2 fused launches unchanged from round 12.

static constexpr int NB    = 196;
static constexpr int NPB   = 512;
static constexpr int BCAP  = 9216;
static constexpr int CHUNK = 4096;
static constexpr int PARTA = 524;

typedef _Float16 f16x8 __attribute__((ext_vector_type(8)));
typedef float    f32x4 __attribute__((ext_vector_type(4)));

// ---------------- shared GEMM1 body (MFMA 16x16x32_f16) ----------------
__device__ inline void gemm1_body(int bid, int tid, _Float16 (*Wt)[136],
                                  const float* __restrict__ X,
                                  const float* __restrict__ W,
                                  __half* __restrict__ Hh, int n) {
    for (int idx = tid; idx < 128 * 128; idx += 256) {
        int k = idx >> 7, c = idx & 127;
        Wt[c][k] = (_Float16)W[idx];
    }
    __syncthreads();
    if (bid * 128 >= n) return;

    int wv = tid >> 6, l = tid & 63;
    int lr = l & 15, lq = l >> 4;
    int rowb = bid * 128 + wv * 32;

    f32x4 acc[2][8];
#pragma unroll
    for (int rt = 0; rt < 2; ++rt)
#pragma unroll
        for (int ct = 0; ct < 8; ++ct) acc[rt][ct] = (f32x4){0.f, 0.f, 0.f, 0.f};

#pragma unroll
    for (int kt = 0; kt < 4; ++kt) {
        int kb = kt * 32 + lq * 8;
        f16x8 af[2];
#pragma unroll
        for (int rt = 0; rt < 2; ++rt) {
            int row = rowb + rt * 16 + lr;
            row = (row < n) ? row : (n - 1);
            const float* xr = X + (size_t)row * 128 + kb;
            float4 xa = *(const float4*)xr;
            float4 xb = *(const float4*)(xr + 4);
            f16x8 a;
            a[0] = (_Float16)xa.x; a[1] = (_Float16)xa.y;
            a[2] = (_Float16)xa.z; a[3] = (_Float16)xa.w;
            a[4] = (_Float16)xb.x; a[5] = (_Float16)xb.y;
            a[6] = (_Float16)xb.z; a[7] = (_Float16)xb.w;
            af[rt] = a;
        }
#pragma unroll
        for (int ct = 0; ct < 8; ++ct) {
            f16x8 bf = *(const f16x8*)&Wt[ct * 16 + lr][kb];
            acc[0][ct] = __builtin_amdgcn_mfma_f32_16x16x32_f16(af[0], bf, acc[0][ct], 0, 0, 0);
            acc[1][ct] = __builtin_amdgcn_mfma_f32_16x16x32_f16(af[1], bf, acc[1][ct], 0, 0, 0);
        }
    }
#pragma unroll
    for (int rt = 0; rt < 2; ++rt)
#pragma unroll
        for (int j = 0; j < 4; ++j) {
            int row = rowb + rt * 16 + lq * 4 + j;
            if (row >= n) continue;
            __half* hr = Hh + (size_t)row * 128 + lr;
#pragma unroll
            for (int ct = 0; ct < 8; ++ct)
                hr[ct * 16] = __float2half(acc[rt][ct][j]);
        }
}

// ---------------- L1: {bucket scatter (3/7) | GEMM1-A (4/7)} ----------------
union SharedL1 {
    _Float16 Wt[128][136];
    struct {
        int hist[NB]; int lofs[NB]; int gbase[NB]; int lcur[NB]; int scanv[256];
        unsigned pkbuf[CHUNK]; unsigned short bbuf[CHUNK];
    } s;
};

__global__ __launch_bounds__(256) void k_scat_gemm1(
        const int* __restrict__ src, const int* __restrict__ dst, int E,
        int* __restrict__ gcursor, unsigned* __restrict__ ebuf,
        const float* __restrict__ X, const float* __restrict__ W,
        __half* __restrict__ Hh, int n, int nchunks) {
    __shared__ SharedL1 sh;
    int q = blockIdx.x / 7, r = blockIdx.x % 7;
    int tid = threadIdx.x;
    if (r < 3) {
        int fid = q * 3 + r;
        if (fid >= nchunks) return;
        long long e0 = (long long)fid * CHUNK;
        int m = (int)(((long long)E - e0 < CHUNK) ? (E - e0) : CHUNK);

        for (int i = tid; i < NB; i += 256) sh.s.hist[i] = 0;
        __syncthreads();

        unsigned pk[16]; int bk[16];
#pragma unroll
        for (int i = 0; i < 16; ++i) {
            int idx = i * 256 + tid;
            bool ok = idx < m;
            long long e = e0 + idx;
            int d = ok ? dst[e] : 0;
            int s = ok ? src[e] : 0;
            bk[i] = ok ? (d >> 9) : -1;
            pk[i] = ((unsigned)(d & 511) << 17) | (unsigned)s;
            if (ok) atomicAdd(&sh.s.hist[bk[i]], 1);
        }
        __syncthreads();
        int v = (tid < NB) ? sh.s.hist[tid] : 0;
        sh.s.scanv[tid] = v;
        __syncthreads();
        for (int off = 1; off < 256; off <<= 1) {
            int add = (tid >= off) ? sh.s.scanv[tid - off] : 0;
            __syncthreads();
            sh.s.scanv[tid] += add;
            __syncthreads();
        }
        if (tid < NB) {
            int ex = sh.s.scanv[tid] - v;
            sh.s.lofs[tid] = ex;
            sh.s.lcur[tid] = ex;
            sh.s.gbase[tid] = (v > 0) ? atomicAdd(&gcursor[tid], v) : 0;
        }
        __syncthreads();
#pragma unroll
        for (int i = 0; i < 16; ++i) {
            if (bk[i] >= 0) {
                int slot = atomicAdd(&sh.s.lcur[bk[i]], 1);
                sh.s.pkbuf[slot] = pk[i];
                sh.s.bbuf[slot] = (unsigned short)bk[i];
            }
        }
        __syncthreads();
        for (int i = tid; i < m; i += 256) {
            int b = sh.s.bbuf[i];
            int rel = sh.s.gbase[b] + (i - sh.s.lofs[b]);
            if (rel < BCAP) ebuf[(size_t)b * BCAP + rel] = sh.s.pkbuf[i];
        }
        return;
    }
    int bid = q * 4 + (r - 3);
    if (bid >= PARTA) return;
    gemm1_body(bid, tid, sh.Wt, X, W, Hh, n);
}

// ---------------- L2: {per-bucket CSR build (3/7) | GEMM1-B (4/7)} ----------------
union SharedL2 {
    _Float16 Wt[128][136];
    struct { int hist[NPB]; int scanv[256]; int rp[NPB]; int reds[256]; } c;
};

__global__ __launch_bounds__(256) void k_csr_gemm1b(
        const unsigned* __restrict__ ebuf, const int* __restrict__ gcursor,
        int* __restrict__ row_ptr, int* __restrict__ col,
        float* __restrict__ dinv, int N_,
        const float* __restrict__ X, const float* __restrict__ W,
        __half* __restrict__ Hh, int n) {
    __shared__ SharedL2 sh;
    int q = blockIdx.x / 7, r = blockIdx.x % 7;
    int tid = threadIdx.x;
    if (r < 3) {
        int b = q * 3 + r;
        if (b >= NB) return;
        int rv = (tid < NB && tid < b) ? min(gcursor[tid], BCAP) : 0;
        sh.c.reds[tid] = rv;
        __syncthreads();
        for (int off = 128; off > 0; off >>= 1) {
            if (tid < off) sh.c.reds[tid] += sh.c.reds[tid + off];
            __syncthreads();
        }
        int base = sh.c.reds[0];
        __syncthreads();

        for (int i = tid; i < NPB; i += 256) sh.c.hist[i] = 0;
        __syncthreads();
        int cntb = min(gcursor[b], BCAP);
        const unsigned* seg = ebuf + (size_t)b * BCAP;
        for (int i = tid; i < cntb; i += 256)
            atomicAdd(&sh.c.hist[seg[i] >> 17], 1);
        __syncthreads();
        int a0 = sh.c.hist[2 * tid], a1 = sh.c.hist[2 * tid + 1];
        int s = a0 + a1;
        sh.c.scanv[tid] = s;
        __syncthreads();
        for (int off = 1; off < 256; off <<= 1) {
            int add = (tid >= off) ? sh.c.scanv[tid - off] : 0;
            __syncthreads();
            sh.c.scanv[tid] += add;
            __syncthreads();
        }
        int excl = sh.c.scanv[tid] - s;
        sh.c.rp[2 * tid] = excl;
        sh.c.rp[2 * tid + 1] = excl + a0;
        __syncthreads();
        int node0 = b * NPB;
        for (int i = tid; i < NPB; i += 256) {
            int node = node0 + i;
            if (node < N_) {
                row_ptr[node] = base + sh.c.rp[i];
                dinv[node] = rsqrtf((float)(sh.c.hist[i] + 1));
            }
        }
        if (tid == 0 && b == NB - 1) row_ptr[N_] = base + cntb;
        __syncthreads();
        for (int i = tid; i < NPB; i += 256) sh.c.rp[i] += base;
        __syncthreads();
        for (int i = tid; i < cntb; i += 256) {
            unsigned pk = seg[i];
            int pos = atomicAdd(&sh.c.rp[pk >> 17], 1);
            col[pos] = (int)(pk & 0x1FFFFu);
        }
        return;
    }
    int bid = PARTA + q * 4 + (r - 3);
    if (bid * 128 >= n) return;
    gemm1_body(bid, tid, sh.Wt, X, W, Hh, n);
}

// ---------- fused {gather128 -> LDS tile -> MFMA GEMM2} ----------
// Block owns 128 nodes. Gather phase: one node per half-wave, fp16 pk_fma
// accumulate, result (x dinv[d]) into aggB[128][136]. Then MFMA with W2.
__global__ __launch_bounds__(256) void k_agg_gemm2(
        const __half* __restrict__ Hs, const float* __restrict__ dinv,
        const int* __restrict__ row_ptr, const int* __restrict__ col,
        const float* __restrict__ W2, const float* __restrict__ b1,
        __half* __restrict__ Hh2, int n) {
    __shared__ _Float16 Wt[64][136];    // W2 transposed [n][k]
    __shared__ _Float16 b1h[128];
    __shared__ _Float16 aggB[128][136]; // gathered tile (pad -> aligned + conflict-free)
    int tid = threadIdx.x;
    for (int idx = tid; idx < 128 * 64; idx += 256) {
        int k = idx >> 6, c = idx & 63;
        Wt[c][k] = (_Float16)W2[idx];
    }
    if (tid < 128) b1h[tid] = (_Float16)b1[tid];

    int wave = tid >> 6, lane = tid & 63;
    int h = lane >> 5, hl = lane & 31;
    int halfbase = h * 32;
    int qi2 = hl >> 4, ql = hl & 15;
    int node0 = blockIdx.x * 128;

    for (int p = 0; p < 16; ++p) {
        int loc = p * 8 + wave * 2 + h;
        int node = node0 + loc;
        f16x8 acc;
#pragma unroll
        for (int i = 0; i < 8; ++i) acc[i] = (_Float16)0.f;
        if (node < n) {
            int beg = row_ptr[node], end = row_ptr[node + 1];
            int deg = end - beg;
            for (int base = 0; base < deg; base += 32) {
                int m = deg - base; if (m > 32) m = 32;
                int cl = (hl < m) ? col[beg + base + hl] : 0;
                for (int j = 0; j < m; j += 16) {
                    int ss[8]; float wf[8];
#pragma unroll
                    for (int t = 0; t < 8; ++t) {
                        int jx = j + t * 2 + qi2;
                        bool ok = jx < m;
                        ss[t] = __shfl(cl, halfbase + (ok ? jx : j));
                        wf[t] = ok ? dinv[ss[t]] : 0.f;
                    }
                    f16x8 uu[8];
#pragma unroll
                    for (int t = 0; t < 8; ++t)
                        uu[t] = *(const f16x8*)(Hs + (size_t)ss[t] * 128 + ql * 8);
#pragma unroll
                    for (int t = 0; t < 8; ++t) {
                        _Float16 wh = (_Float16)wf[t];
                        f16x8 ws;
#pragma unroll
                        for (int i = 0; i < 8; ++i) ws[i] = wh;
                        acc = uu[t] * ws + acc;      // v_pk_fma_f16 x4
                    }
                }
            }
        }
        // combine the two qi2 partials (xor 16) on packed data
        uint4 ai = *(uint4*)&acc;
        uint4 bi;
        bi.x = __shfl_xor((int)ai.x, 16); bi.y = __shfl_xor((int)ai.y, 16);
        bi.z = __shfl_xor((int)ai.z, 16); bi.w = __shfl_xor((int)ai.w, 16);
        f16x8 other = *(f16x8*)&bi;
        acc = acc + other;
        if (qi2 == 0) {
            f16x8 o;
            if (node < n) {
                f16x8 sv = *(const f16x8*)(Hs + (size_t)node * 128 + ql * 8);
                float dn = dinv[node];
#pragma unroll
                for (int i = 0; i < 8; ++i) {
                    float s = (float)acc[i] + dn * (float)sv[i];
                    o[i] = (_Float16)(s * dn);
                }
            } else {
#pragma unroll
                for (int i = 0; i < 8; ++i) o[i] = (_Float16)0.f;
            }
            *(f16x8*)&aggB[loc][ql * 8] = o;
        }
    }
    __syncthreads();
    // ---- MFMA GEMM2: Hh2 = fp16((relu(aggB + b1) @ W2) * dinv) ----
    int lr = lane & 15, lq = lane >> 4;
    int rowbL = wave * 32;
    f32x4 acc2[2][4];
#pragma unroll
    for (int rt = 0; rt < 2; ++rt)
#pragma unroll
        for (int ct = 0; ct < 4; ++ct) acc2[rt][ct] = (f32x4){0.f, 0.f, 0.f, 0.f};

#pragma unroll
    for (int kt = 0; kt < 4; ++kt) {
        int kb = kt * 32 + lq * 8;
        f16x8 bb = *(const f16x8*)&b1h[kb];
        f16x8 af[2];
#pragma unroll
        for (int rt = 0; rt < 2; ++rt) {
            f16x8 a = *(const f16x8*)&aggB[rowbL + rt * 16 + lr][kb];
            a = a + bb;
#pragma unroll
            for (int i = 0; i < 8; ++i)
                a[i] = (a[i] > (_Float16)0.f) ? a[i] : (_Float16)0.f;
            af[rt] = a;
        }
#pragma unroll
        for (int ct = 0; ct < 4; ++ct) {
            f16x8 bf = *(const f16x8*)&Wt[ct * 16 + lr][kb];
            acc2[0][ct] = __builtin_amdgcn_mfma_f32_16x16x32_f16(af[0], bf, acc2[0][ct], 0, 0, 0);
            acc2[1][ct] = __builtin_amdgcn_mfma_f32_16x16x32_f16(af[1], bf, acc2[1][ct], 0, 0, 0);
        }
    }
#pragma unroll
    for (int rt = 0; rt < 2; ++rt)
#pragma unroll
        for (int j = 0; j < 4; ++j) {
            int row = node0 + rowbL + rt * 16 + lq * 4 + j;
            if (row >= n) continue;
            float dn = dinv[row];
            __half* hr = Hh2 + (size_t)row * 64 + lr;
#pragma unroll
            for (int ct = 0; ct < 4; ++ct)
                hr[ct * 16] = __float2half(acc2[rt][ct][j] * dn);
        }
}

// ---------- layer-2 gather (64-d) + FC: half-wave/node, fp16 pk accumulate ----------
__global__ __launch_bounds__(256) void k_gather_fc(const __half* __restrict__ Hs,
                                                   const float* __restrict__ dinv,
                                                   const int* __restrict__ row_ptr,
                                                   const int* __restrict__ col,
                                                   const float* __restrict__ b2,
                                                   const float* __restrict__ Wfc,
                                                   const float* __restrict__ bfc,
                                                   float* __restrict__ out, int n) {
    int wave = threadIdx.x >> 6;
    int lane = threadIdx.x & 63;
    int h = lane >> 5, hl = lane & 31;
    int halfbase = h * 32;
    int oi2 = hl >> 3, ol = hl & 7;
    float wrowA[10], wrowB[10];
#pragma unroll
    for (int j = 0; j < 10; ++j) {
        wrowA[j] = Wfc[(2 * hl) * 10 + j];
        wrowB[j] = Wfc[(2 * hl + 1) * 10 + j];
    }
    float2 b2v = *(const float2*)(b2 + 2 * hl);

    int node = blockIdx.x * 8 + wave * 2 + h;
    if (node >= n) return;
    int beg = row_ptr[node], end = row_ptr[node + 1];
    int deg = end - beg;

    f16x8 acc;
#pragma unroll
    for (int i = 0; i < 8; ++i) acc[i] = (_Float16)0.f;

    for (int base = 0; base < deg; base += 32) {
        int m = deg - base; if (m > 32) m = 32;
        int cl = (hl < m) ? col[beg + base + hl] : 0;
        for (int j = 0; j < m; j += 16) {
            int ss[4]; float wf[4];
#pragma unroll
            for (int t = 0; t < 4; ++t) {
                int jx = j + t * 4 + oi2;
                bool ok = jx < m;
                ss[t] = __shfl(cl, halfbase + (ok ? jx : j));
                wf[t] = ok ? 1.f : 0.f;
            }
            f16x8 uu[4];
#pragma unroll
            for (int t = 0; t < 4; ++t)
                uu[t] = *(const f16x8*)(Hs + (size_t)ss[t] * 64 + ol * 8);
#pragma unroll
            for (int t = 0; t < 4; ++t) {
                _Float16 wh = (_Float16)wf[t];
                f16x8 ws;
#pragma unroll
                for (int i = 0; i < 8; ++i) ws[i] = wh;
                acc = uu[t] * ws + acc;
            }
        }
    }
    // reduce across oi2 (xor 16, xor 8) on packed data
#pragma unroll
    for (int off = 16; off >= 8; off >>= 1) {
        uint4 ai = *(uint4*)&acc;
        uint4 bi;
        bi.x = __shfl_xor((int)ai.x, off); bi.y = __shfl_xor((int)ai.y, off);
        bi.z = __shfl_xor((int)ai.z, off); bi.w = __shfl_xor((int)ai.w, off);
        f16x8 other = *(f16x8*)&bi;
        acc = acc + other;
    }
    float av[8];
#pragma unroll
    for (int v = 0; v < 8; ++v) av[v] = (float)acc[v];
    // lane owns cols (2hl, 2hl+1): both live in group (hl>>2) at elems 2(hl&3), +1
    int srcl = halfbase + (hl >> 2);
    float vals[8];
#pragma unroll
    for (int v = 0; v < 8; ++v) vals[v] = __shfl(av[v], srcl);
    int e = (hl & 3) * 2;
    float aggA = vals[0], aggB2 = vals[1];
#pragma unroll
    for (int v = 2; v < 8; v += 2) {
        aggA = (e == v) ? vals[v] : aggA;
        aggB2 = (e == v) ? vals[v + 1] : aggB2;
    }
    float2 sf = __half22float2(*(const __half2*)(Hs + (size_t)node * 64 + 2 * hl));
    float dn = dinv[node];
    float vA = fmaxf((aggA + sf.x) * dn + b2v.x, 0.f);
    float vB = fmaxf((aggB2 + sf.y) * dn + b2v.y, 0.f);
    float p[10];
#pragma unroll
    for (int j = 0; j < 10; ++j) p[j] = vA * wrowA[j] + vB * wrowB[j];
#pragma unroll
    for (int off = 16; off > 0; off >>= 1)
#pragma unroll
        for (int j = 0; j < 10; ++j) p[j] += __shfl_xor(p[j], off);
    if (hl == 0) {
        float* o = out + (size_t)node * 10;
#pragma unroll
        for (int j = 0; j < 10; ++j) o[j] = p[j] + bfc[j];
    }
}

static inline int cdiv(long long a, int b) { return (int)((a + b - 1) / b); }

extern "C" void kernel_launch(void* const* d_in, const int* in_sizes, int n_in,
                              void* d_out, int out_size, void* d_ws, size_t ws_size,
                              hipStream_t stream) {
    const float* x   = (const float*)d_in[0];
    const int*   ei  = (const int*)d_in[1];
    const float* W1  = (const float*)d_in[2];
    const float* b1  = (const float*)d_in[3];
    const float* W2  = (const float*)d_in[4];
    const float* b2  = (const float*)d_in[5];
    const float* Wfc = (const float*)d_in[6];
    const float* bfc = (const float*)d_in[7];
    float* out = (float*)d_out;

    const int N = in_sizes[0] / 128;   // 100000
    const int E = in_sizes[1] / 2;     // 1600000
    const int* src = ei;
    const int* dst = ei + E;

    char* ws = (char*)d_ws;
    size_t off = 0;
    auto alloc = [&](size_t bytes) { void* p = ws + off; off = (off + bytes + 255) & ~(size_t)255; return p; };
    float*    dinv    = (float*)   alloc((size_t)N * 4);
    int*      row_ptr = (int*)     alloc((size_t)(N + 1) * 4);
    int*      gcursor = (int*)     alloc((size_t)NB * 4);
    unsigned* ebuf    = (unsigned*)alloc((size_t)NB * BCAP * 4);
    int*      col     = (int*)     alloc((size_t)E * 4);
    __half*   Hh1     = (__half*)  alloc((size_t)N * 128 * 2);
    __half*   Hh2     = (__half*)  alloc((size_t)N * 64 * 2);

    hipMemsetAsync(gcursor, 0, (size_t)NB * 4, stream);

    const int nchunks = cdiv(E, CHUNK);               // 391
    const int groupsL1 = max(cdiv(nchunks, 3), cdiv(PARTA, 4));
    k_scat_gemm1<<<groupsL1 * 7, 256, 0, stream>>>(
        src, dst, E, gcursor, ebuf, x, W1, Hh1, N, nchunks);

    const int gemmTotal = cdiv(N, 128);               // 782
    const int groupsL2 = max(cdiv(NB, 3), cdiv(gemmTotal - PARTA, 4));
    k_csr_gemm1b<<<groupsL2 * 7, 256, 0, stream>>>(
        ebuf, gcursor, row_ptr, col, dinv, N, x, W1, Hh1, N);

    // fused layer-1 aggregate + layer-2 transform
    k_agg_gemm2<<<cdiv(N, 128), 256, 0, stream>>>(Hh1, dinv, row_ptr, col,
                                                  W2, b1, Hh2, N);

    // layer-2 aggregate + FC head (writes d_out)
    k_gather_fc<<<cdiv(N, 8), 256, 0, stream>>>(Hh2, dinv, row_ptr, col,
                                                b2, Wfc, bfc, out, N);
}

// Round 14
// 267.499 us; speedup vs baseline: 1.3251x; 1.3251x over previous
//
#include <hip/hip_runtime.h>
#include <hip/hip_fp16.h>

// GCN 2-layer + FC. Round 14: round-12 structure (separate gather128 / gemm2 —
// the LDS fusion of r13 destroyed gather parallelism, 168us vs 62+25) with
// r13's validated fp16 pk_fma accumulation in both gathers.

static constexpr int NB    = 196;
static constexpr int NPB   = 512;
static constexpr int BCAP  = 9216;
static constexpr int CHUNK = 4096;
static constexpr int PARTA = 524;

typedef _Float16 f16x8 __attribute__((ext_vector_type(8)));
typedef float    f32x4 __attribute__((ext_vector_type(4)));

// ---------------- shared GEMM1 body (MFMA 16x16x32_f16) ----------------
__device__ inline void gemm1_body(int bid, int tid, _Float16 (*Wt)[136],
                                  const float* __restrict__ X,
                                  const float* __restrict__ W,
                                  __half* __restrict__ Hh, int n) {
    for (int idx = tid; idx < 128 * 128; idx += 256) {
        int k = idx >> 7, c = idx & 127;
        Wt[c][k] = (_Float16)W[idx];
    }
    __syncthreads();
    if (bid * 128 >= n) return;

    int wv = tid >> 6, l = tid & 63;
    int lr = l & 15, lq = l >> 4;
    int rowb = bid * 128 + wv * 32;

    f32x4 acc[2][8];
#pragma unroll
    for (int rt = 0; rt < 2; ++rt)
#pragma unroll
        for (int ct = 0; ct < 8; ++ct) acc[rt][ct] = (f32x4){0.f, 0.f, 0.f, 0.f};

#pragma unroll
    for (int kt = 0; kt < 4; ++kt) {
        int kb = kt * 32 + lq * 8;
        f16x8 af[2];
#pragma unroll
        for (int rt = 0; rt < 2; ++rt) {
            int row = rowb + rt * 16 + lr;
            row = (row < n) ? row : (n - 1);
            const float* xr = X + (size_t)row * 128 + kb;
            float4 xa = *(const float4*)xr;
            float4 xb = *(const float4*)(xr + 4);
            f16x8 a;
            a[0] = (_Float16)xa.x; a[1] = (_Float16)xa.y;
            a[2] = (_Float16)xa.z; a[3] = (_Float16)xa.w;
            a[4] = (_Float16)xb.x; a[5] = (_Float16)xb.y;
            a[6] = (_Float16)xb.z; a[7] = (_Float16)xb.w;
            af[rt] = a;
        }
#pragma unroll
        for (int ct = 0; ct < 8; ++ct) {
            f16x8 bf = *(const f16x8*)&Wt[ct * 16 + lr][kb];
            acc[0][ct] = __builtin_amdgcn_mfma_f32_16x16x32_f16(af[0], bf, acc[0][ct], 0, 0, 0);
            acc[1][ct] = __builtin_amdgcn_mfma_f32_16x16x32_f16(af[1], bf, acc[1][ct], 0, 0, 0);
        }
    }
#pragma unroll
    for (int rt = 0; rt < 2; ++rt)
#pragma unroll
        for (int j = 0; j < 4; ++j) {
            int row = rowb + rt * 16 + lq * 4 + j;
            if (row >= n) continue;
            __half* hr = Hh + (size_t)row * 128 + lr;
#pragma unroll
            for (int ct = 0; ct < 8; ++ct)
                hr[ct * 16] = __float2half(acc[rt][ct][j]);
        }
}

// ---------------- L1: {bucket scatter (3/7) | GEMM1-A (4/7)} ----------------
union SharedL1 {
    _Float16 Wt[128][136];
    struct {
        int hist[NB]; int lofs[NB]; int gbase[NB]; int lcur[NB]; int scanv[256];
        unsigned pkbuf[CHUNK]; unsigned short bbuf[CHUNK];
    } s;
};

__global__ __launch_bounds__(256) void k_scat_gemm1(
        const int* __restrict__ src, const int* __restrict__ dst, int E,
        int* __restrict__ gcursor, unsigned* __restrict__ ebuf,
        const float* __restrict__ X, const float* __restrict__ W,
        __half* __restrict__ Hh, int n, int nchunks) {
    __shared__ SharedL1 sh;
    int q = blockIdx.x / 7, r = blockIdx.x % 7;
    int tid = threadIdx.x;
    if (r < 3) {
        int fid = q * 3 + r;
        if (fid >= nchunks) return;
        long long e0 = (long long)fid * CHUNK;
        int m = (int)(((long long)E - e0 < CHUNK) ? (E - e0) : CHUNK);

        for (int i = tid; i < NB; i += 256) sh.s.hist[i] = 0;
        __syncthreads();

        unsigned pk[16]; int bk[16];
#pragma unroll
        for (int i = 0; i < 16; ++i) {
            int idx = i * 256 + tid;
            bool ok = idx < m;
            long long e = e0 + idx;
            int d = ok ? dst[e] : 0;
            int s = ok ? src[e] : 0;
            bk[i] = ok ? (d >> 9) : -1;
            pk[i] = ((unsigned)(d & 511) << 17) | (unsigned)s;
            if (ok) atomicAdd(&sh.s.hist[bk[i]], 1);
        }
        __syncthreads();
        int v = (tid < NB) ? sh.s.hist[tid] : 0;
        sh.s.scanv[tid] = v;
        __syncthreads();
        for (int off = 1; off < 256; off <<= 1) {
            int add = (tid >= off) ? sh.s.scanv[tid - off] : 0;
            __syncthreads();
            sh.s.scanv[tid] += add;
            __syncthreads();
        }
        if (tid < NB) {
            int ex = sh.s.scanv[tid] - v;
            sh.s.lofs[tid] = ex;
            sh.s.lcur[tid] = ex;
            sh.s.gbase[tid] = (v > 0) ? atomicAdd(&gcursor[tid], v) : 0;
        }
        __syncthreads();
#pragma unroll
        for (int i = 0; i < 16; ++i) {
            if (bk[i] >= 0) {
                int slot = atomicAdd(&sh.s.lcur[bk[i]], 1);
                sh.s.pkbuf[slot] = pk[i];
                sh.s.bbuf[slot] = (unsigned short)bk[i];
            }
        }
        __syncthreads();
        for (int i = tid; i < m; i += 256) {
            int b = sh.s.bbuf[i];
            int rel = sh.s.gbase[b] + (i - sh.s.lofs[b]);
            if (rel < BCAP) ebuf[(size_t)b * BCAP + rel] = sh.s.pkbuf[i];
        }
        return;
    }
    int bid = q * 4 + (r - 3);
    if (bid >= PARTA) return;
    gemm1_body(bid, tid, sh.Wt, X, W, Hh, n);
}

// ---------------- L2: {per-bucket CSR build (3/7) | GEMM1-B (4/7)} ----------------
union SharedL2 {
    _Float16 Wt[128][136];
    struct { int hist[NPB]; int scanv[256]; int rp[NPB]; int reds[256]; } c;
};

__global__ __launch_bounds__(256) void k_csr_gemm1b(
        const unsigned* __restrict__ ebuf, const int* __restrict__ gcursor,
        int* __restrict__ row_ptr, int* __restrict__ col,
        float* __restrict__ dinv, int N_,
        const float* __restrict__ X, const float* __restrict__ W,
        __half* __restrict__ Hh, int n) {
    __shared__ SharedL2 sh;
    int q = blockIdx.x / 7, r = blockIdx.x % 7;
    int tid = threadIdx.x;
    if (r < 3) {
        int b = q * 3 + r;
        if (b >= NB) return;
        int rv = (tid < NB && tid < b) ? min(gcursor[tid], BCAP) : 0;
        sh.c.reds[tid] = rv;
        __syncthreads();
        for (int off = 128; off > 0; off >>= 1) {
            if (tid < off) sh.c.reds[tid] += sh.c.reds[tid + off];
            __syncthreads();
        }
        int base = sh.c.reds[0];
        __syncthreads();

        for (int i = tid; i < NPB; i += 256) sh.c.hist[i] = 0;
        __syncthreads();
        int cntb = min(gcursor[b], BCAP);
        const unsigned* seg = ebuf + (size_t)b * BCAP;
        for (int i = tid; i < cntb; i += 256)
            atomicAdd(&sh.c.hist[seg[i] >> 17], 1);
        __syncthreads();
        int a0 = sh.c.hist[2 * tid], a1 = sh.c.hist[2 * tid + 1];
        int s = a0 + a1;
        sh.c.scanv[tid] = s;
        __syncthreads();
        for (int off = 1; off < 256; off <<= 1) {
            int add = (tid >= off) ? sh.c.scanv[tid - off] : 0;
            __syncthreads();
            sh.c.scanv[tid] += add;
            __syncthreads();
        }
        int excl = sh.c.scanv[tid] - s;
        sh.c.rp[2 * tid] = excl;
        sh.c.rp[2 * tid + 1] = excl + a0;
        __syncthreads();
        int node0 = b * NPB;
        for (int i = tid; i < NPB; i += 256) {
            int node = node0 + i;
            if (node < N_) {
                row_ptr[node] = base + sh.c.rp[i];
                dinv[node] = rsqrtf((float)(sh.c.hist[i] + 1));
            }
        }
        if (tid == 0 && b == NB - 1) row_ptr[N_] = base + cntb;
        __syncthreads();
        for (int i = tid; i < NPB; i += 256) sh.c.rp[i] += base;
        __syncthreads();
        for (int i = tid; i < cntb; i += 256) {
            unsigned pk = seg[i];
            int pos = atomicAdd(&sh.c.rp[pk >> 17], 1);
            col[pos] = (int)(pk & 0x1FFFFu);
        }
        return;
    }
    int bid = PARTA + q * 4 + (r - 3);
    if (bid * 128 >= n) return;
    gemm1_body(bid, tid, sh.Wt, X, W, Hh, n);
}

// ---------- layer-1 gather (128-d fp16): half-wave/node, pk_fma accumulate ----------
__global__ __launch_bounds__(256) void k_gather128(const __half* __restrict__ Hs,
                                                   const float* __restrict__ dinv,
                                                   const int* __restrict__ row_ptr,
                                                   const int* __restrict__ col,
                                                   __half* __restrict__ outh, int n) {
    int wave = threadIdx.x >> 6;
    int lane = threadIdx.x & 63;
    int h = lane >> 5, hl = lane & 31;
    int halfbase = h * 32;
    int qi2 = hl >> 4, ql = hl & 15;
    int node = blockIdx.x * 8 + wave * 2 + h;
    if (node >= n) return;
    int beg = row_ptr[node], end = row_ptr[node + 1];
    int deg = end - beg;

    f16x8 acc;
#pragma unroll
    for (int i = 0; i < 8; ++i) acc[i] = (_Float16)0.f;

    for (int base = 0; base < deg; base += 32) {
        int m = deg - base; if (m > 32) m = 32;
        int cl = (hl < m) ? col[beg + base + hl] : 0;
        for (int j = 0; j < m; j += 16) {
            int ss[8]; float wf[8];
#pragma unroll
            for (int t = 0; t < 8; ++t) {
                int jx = j + t * 2 + qi2;
                bool ok = jx < m;
                ss[t] = __shfl(cl, halfbase + (ok ? jx : j));
                wf[t] = ok ? dinv[ss[t]] : 0.f;
            }
            f16x8 uu[8];
#pragma unroll
            for (int t = 0; t < 8; ++t)
                uu[t] = *(const f16x8*)(Hs + (size_t)ss[t] * 128 + ql * 8);
#pragma unroll
            for (int t = 0; t < 8; ++t) {
                _Float16 wh = (_Float16)wf[t];
                f16x8 ws;
#pragma unroll
                for (int i = 0; i < 8; ++i) ws[i] = wh;
                acc = uu[t] * ws + acc;      // v_pk_fma_f16 x4
            }
        }
    }
    // combine the two qi2 partials (xor 16) on packed data
    uint4 ai = *(uint4*)&acc;
    uint4 bi;
    bi.x = __shfl_xor((int)ai.x, 16); bi.y = __shfl_xor((int)ai.y, 16);
    bi.z = __shfl_xor((int)ai.z, 16); bi.w = __shfl_xor((int)ai.w, 16);
    f16x8 other = *(f16x8*)&bi;
    acc = acc + other;
    if (qi2 == 0) {
        f16x8 sv = *(const f16x8*)(Hs + (size_t)node * 128 + ql * 8);
        float dn = dinv[node];
        f16x8 o;
#pragma unroll
        for (int i = 0; i < 8; ++i) {
            float s = (float)acc[i] + dn * (float)sv[i];
            o[i] = (_Float16)(s * dn);
        }
        *(f16x8*)(outh + (size_t)node * 128 + ql * 8) = o;
    }
}

// ---------- GEMM2 (MFMA): Hh2 = fp16((relu(A+b1) @ W2) * dinv), A fp16 ----------
__global__ __launch_bounds__(256) void k_gemm2(const __half* __restrict__ A,
                                               const float* __restrict__ W2,
                                               const float* __restrict__ b1,
                                               const float* __restrict__ dinv,
                                               __half* __restrict__ Hh2, int n) {
    __shared__ _Float16 Wt[64][136];
    __shared__ _Float16 b1h[128];
    int tid = threadIdx.x;
    for (int idx = tid; idx < 128 * 64; idx += 256) {
        int k = idx >> 6, c = idx & 63;
        Wt[c][k] = (_Float16)W2[idx];
    }
    if (tid < 128) b1h[tid] = (_Float16)b1[tid];
    __syncthreads();

    int bid = blockIdx.x;
    if (bid * 128 >= n) return;
    int wv = tid >> 6, l = tid & 63;
    int lr = l & 15, lq = l >> 4;
    int rowb = bid * 128 + wv * 32;

    f32x4 acc[2][4];
#pragma unroll
    for (int rt = 0; rt < 2; ++rt)
#pragma unroll
        for (int ct = 0; ct < 4; ++ct) acc[rt][ct] = (f32x4){0.f, 0.f, 0.f, 0.f};

#pragma unroll
    for (int kt = 0; kt < 4; ++kt) {
        int kb = kt * 32 + lq * 8;
        f16x8 bb = *(const f16x8*)&b1h[kb];
        f16x8 af[2];
#pragma unroll
        for (int rt = 0; rt < 2; ++rt) {
            int row = rowb + rt * 16 + lr;
            row = (row < n) ? row : (n - 1);
            f16x8 a = *(const f16x8*)(A + (size_t)row * 128 + kb);
            a = a + bb;
#pragma unroll
            for (int i = 0; i < 8; ++i)
                a[i] = (a[i] > (_Float16)0.f) ? a[i] : (_Float16)0.f;
            af[rt] = a;
        }
#pragma unroll
        for (int ct = 0; ct < 4; ++ct) {
            f16x8 bf = *(const f16x8*)&Wt[ct * 16 + lr][kb];
            acc[0][ct] = __builtin_amdgcn_mfma_f32_16x16x32_f16(af[0], bf, acc[0][ct], 0, 0, 0);
            acc[1][ct] = __builtin_amdgcn_mfma_f32_16x16x32_f16(af[1], bf, acc[1][ct], 0, 0, 0);
        }
    }
#pragma unroll
    for (int rt = 0; rt < 2; ++rt)
#pragma unroll
        for (int j = 0; j < 4; ++j) {
            int row = rowb + rt * 16 + lq * 4 + j;
            if (row >= n) continue;
            float dn = dinv[row];
            __half* hr = Hh2 + (size_t)row * 64 + lr;
#pragma unroll
            for (int ct = 0; ct < 4; ++ct)
                hr[ct * 16] = __float2half(acc[rt][ct][j] * dn);
        }
}

// ---------- layer-2 gather (64-d) + FC: half-wave/node, pk_fma accumulate ----------
__global__ __launch_bounds__(256) void k_gather_fc(const __half* __restrict__ Hs,
                                                   const float* __restrict__ dinv,
                                                   const int* __restrict__ row_ptr,
                                                   const int* __restrict__ col,
                                                   const float* __restrict__ b2,
                                                   const float* __restrict__ Wfc,
                                                   const float* __restrict__ bfc,
                                                   float* __restrict__ out, int n) {
    int wave = threadIdx.x >> 6;
    int lane = threadIdx.x & 63;
    int h = lane >> 5, hl = lane & 31;
    int halfbase = h * 32;
    int oi2 = hl >> 3, ol = hl & 7;
    float wrowA[10], wrowB[10];
#pragma unroll
    for (int j = 0; j < 10; ++j) {
        wrowA[j] = Wfc[(2 * hl) * 10 + j];
        wrowB[j] = Wfc[(2 * hl + 1) * 10 + j];
    }
    float2 b2v = *(const float2*)(b2 + 2 * hl);

    int node = blockIdx.x * 8 + wave * 2 + h;
    if (node >= n) return;
    int beg = row_ptr[node], end = row_ptr[node + 1];
    int deg = end - beg;

    f16x8 acc;
#pragma unroll
    for (int i = 0; i < 8; ++i) acc[i] = (_Float16)0.f;

    for (int base = 0; base < deg; base += 32) {
        int m = deg - base; if (m > 32) m = 32;
        int cl = (hl < m) ? col[beg + base + hl] : 0;
        for (int j = 0; j < m; j += 16) {
            int ss[4]; float wf[4];
#pragma unroll
            for (int t = 0; t < 4; ++t) {
                int jx = j + t * 4 + oi2;
                bool ok = jx < m;
                ss[t] = __shfl(cl, halfbase + (ok ? jx : j));
                wf[t] = ok ? 1.f : 0.f;
            }
            f16x8 uu[4];
#pragma unroll
            for (int t = 0; t < 4; ++t)
                uu[t] = *(const f16x8*)(Hs + (size_t)ss[t] * 64 + ol * 8);
#pragma unroll
            for (int t = 0; t < 4; ++t) {
                _Float16 wh = (_Float16)wf[t];
                f16x8 ws;
#pragma unroll
                for (int i = 0; i < 8; ++i) ws[i] = wh;
                acc = uu[t] * ws + acc;
            }
        }
    }
#pragma unroll
    for (int off = 16; off >= 8; off >>= 1) {
        uint4 ai = *(uint4*)&acc;
        uint4 bi;
        bi.x = __shfl_xor((int)ai.x, off); bi.y = __shfl_xor((int)ai.y, off);
        bi.z = __shfl_xor((int)ai.z, off); bi.w = __shfl_xor((int)ai.w, off);
        f16x8 other = *(f16x8*)&bi;
        acc = acc + other;
    }
    float av[8];
#pragma unroll
    for (int v = 0; v < 8; ++v) av[v] = (float)acc[v];
    int srcl = halfbase + (hl >> 2);
    float vals[8];
#pragma unroll
    for (int v = 0; v < 8; ++v) vals[v] = __shfl(av[v], srcl);
    int e = (hl & 3) * 2;
    float aggA = vals[0], aggB2 = vals[1];
#pragma unroll
    for (int v = 2; v < 8; v += 2) {
        aggA = (e == v) ? vals[v] : aggA;
        aggB2 = (e == v) ? vals[v + 1] : aggB2;
    }
    float2 sf = __half22float2(*(const __half2*)(Hs + (size_t)node * 64 + 2 * hl));
    float dn = dinv[node];
    float vA = fmaxf((aggA + sf.x) * dn + b2v.x, 0.f);
    float vB = fmaxf((aggB2 + sf.y) * dn + b2v.y, 0.f);
    float p[10];
#pragma unroll
    for (int j = 0; j < 10; ++j) p[j] = vA * wrowA[j] + vB * wrowB[j];
#pragma unroll
    for (int off = 16; off > 0; off >>= 1)
#pragma unroll
        for (int j = 0; j < 10; ++j) p[j] += __shfl_xor(p[j], off);
    if (hl == 0) {
        float* o = out + (size_t)node * 10;
#pragma unroll
        for (int j = 0; j < 10; ++j) o[j] = p[j] + bfc[j];
    }
}

static inline int cdiv(long long a, int b) { return (int)((a + b - 1) / b); }

extern "C" void kernel_launch(void* const* d_in, const int* in_sizes, int n_in,
                              void* d_out, int out_size, void* d_ws, size_t ws_size,
                              hipStream_t stream) {
    const float* x   = (const float*)d_in[0];
    const int*   ei  = (const int*)d_in[1];
    const float* W1  = (const float*)d_in[2];
    const float* b1  = (const float*)d_in[3];
    const float* W2  = (const float*)d_in[4];
    const float* b2  = (const float*)d_in[5];
    const float* Wfc = (const float*)d_in[6];
    const float* bfc = (const float*)d_in[7];
    float* out = (float*)d_out;

    const int N = in_sizes[0] / 128;   // 100000
    const int E = in_sizes[1] / 2;     // 1600000
    const int* src = ei;
    const int* dst = ei + E;

    char* ws = (char*)d_ws;
    size_t off = 0;
    auto alloc = [&](size_t bytes) { void* p = ws + off; off = (off + bytes + 255) & ~(size_t)255; return p; };
    float*    dinv    = (float*)   alloc((size_t)N * 4);
    int*      row_ptr = (int*)     alloc((size_t)(N + 1) * 4);
    int*      gcursor = (int*)     alloc((size_t)NB * 4);
    unsigned* ebuf    = (unsigned*)alloc((size_t)NB * BCAP * 4);
    int*      col     = (int*)     alloc((size_t)E * 4);
    __half*   Hh1     = (__half*)  alloc((size_t)N * 128 * 2);
    __half*   Ah1     = (__half*)  alloc((size_t)N * 128 * 2);
    __half*   Hh2     = (__half*)  alloc((size_t)N * 64 * 2);

    hipMemsetAsync(gcursor, 0, (size_t)NB * 4, stream);

    const int nchunks = cdiv(E, CHUNK);               // 391
    const int groupsL1 = max(cdiv(nchunks, 3), cdiv(PARTA, 4));
    k_scat_gemm1<<<groupsL1 * 7, 256, 0, stream>>>(
        src, dst, E, gcursor, ebuf, x, W1, Hh1, N, nchunks);

    const int gemmTotal = cdiv(N, 128);               // 782
    const int groupsL2 = max(cdiv(NB, 3), cdiv(gemmTotal - PARTA, 4));
    k_csr_gemm1b<<<groupsL2 * 7, 256, 0, stream>>>(
        ebuf, gcursor, row_ptr, col, dinv, N, x, W1, Hh1, N);

    // layer 1 aggregate (2 nodes per wave, packed fp16 accumulate)
    k_gather128<<<cdiv(N, 8), 256, 0, stream>>>(Hh1, dinv, row_ptr, col, Ah1, N);

    // layer 2 transform then aggregate+FC (writes d_out)
    k_gemm2<<<cdiv(N, 128), 256, 0, stream>>>(Ah1, W2, b1, dinv, Hh2, N);
    k_gather_fc<<<cdiv(N, 8), 256, 0, stream>>>(Hh2, dinv, row_ptr, col,
                                                b2, Wfc, bfc, out, N);
}